// Round 1
// baseline (2126.734 us; speedup 1.0000x reference)
//
#include <hip/hip_runtime.h>
#include <math.h>

#ifndef M_PI
#define M_PI 3.14159265358979323846
#endif

// Problem constants (from the reference)
constexpr int   NSAMP = 2048;
constexpr int   NN    = NSAMP * NSAMP;            // 2^22
constexpr float STEPf = 2048.0f / 2047.0f;        // linspace(-1024,1024,2048) step
constexpr float DXf   = 6.0e-6f;                  // 3e-6 / 0.5
constexpr float EPSf  = 2.2204e-16f;
constexpr float Kf    = (float)(2.0 * M_PI / 3.55e-7);  // ~1.7698956e7

// Numerical-Recipes J1, fp32, matching the reference's branch structure.
__device__ __forceinline__ float bessel_j1f(float x) {
    float ax = fabsf(x);
    if (ax < 8.0f) {
        // small-argument rational approximation (xc == x here, |x| < 8)
        float y   = x * x;
        float num = x * (72362614232.0f + y * (-7895059235.0f + y * (242396853.1f +
                    y * (-2972611.439f + y * (15704.48260f + y * (-30.16036606f))))));
        float den = 144725228442.0f + y * (2300535178.0f + y * (18583304.74f +
                    y * (99447.43394f + y * (376.9991397f + y))));
        return num / den;
    } else {
        float z  = 8.0f / ax;
        float y2 = z * z;
        float xx = ax - 2.356194491f;
        float p1 = 1.0f + y2 * (0.183105e-2f + y2 * (-0.3516396496e-4f +
                   y2 * (0.2457520174e-5f + y2 * (-0.240337019e-6f))));
        float p2 = 0.04687499995f + y2 * (-0.2002690873e-3f + y2 * (0.8449199096e-5f +
                   y2 * (-0.88228987e-6f + y2 * 0.105787412e-6f)));
        float s, c;
        sincosf(xx, &s, &c);
        float r = sqrtf(0.636619772f / ax) * (c * p1 - z * s * p2);
        return copysignf(r, x);
    }
}

// Gather per-(batch,particle) parameters and precompute per-set constants.
// prm layout: [(b*4+p)*8 + k], k = {xm, ym, carg_h, camp_h, cph_h, carg_g, camp_g, cph_g}
__global__ void gather_params_kernel(const float* __restrict__ yh,
                                     const float* __restrict__ ygt,
                                     const int*   __restrict__ xs,
                                     const int*   __restrict__ ys,
                                     float* __restrict__ prm,
                                     double* __restrict__ acc) {
    int t = threadIdx.x;
    if (t == 0) *acc = 0.0;   // zero the accumulator every launch (graph replay safe)
    if (t < 8) {
        const int M = 512;
        int b = t >> 2, p = t & 3;
        int ix = xs[b * 4 + p];
        int iy = ys[b * 4 + p];
        float rs_h = 50.0f  * yh [((b * 3 + 2) * M + iy) * M + ix];
        float zs_h = 200.0f * yh [((b * 3 + 1) * M + iy) * M + ix];
        float rs_g =          ygt[((b * 5 + 2) * M + iy) * M + ix];
        float zs_g =          ygt[((b * 5 + 1) * M + iy) * M + ix];
        // physical units, same op order as the reference (rs*DR, zs*DZ)
        float rph = rs_h * 1e-6f, zph = zs_h * 1e-3f;
        float rpg = rs_g * 1e-6f, zpg = zs_g * 1e-3f;
        float* o = prm + t * 8;
        o[0] = ((float)(ix * 4) - 1024.0f) * DXf;   // xm
        o[1] = ((float)(iy * 4) - 1024.0f) * DXf;   // ym
        o[2] = Kf * rph / zph;          // arg  = carg * rho
        o[3] = 0.5f * rph;              // amp  = camp / rho * J1(arg)
        o[4] = Kf / (2.0f * zph);       // phase = rho^2 * cph
        o[5] = Kf * rpg / zpg;
        o[6] = 0.5f * rpg;
        o[7] = Kf / (2.0f * zpg);
    }
}

__global__ __launch_bounds__(256) void holo_mse_kernel(const float* __restrict__ prm,
                                                       double* __restrict__ acc) {
    __shared__ float sp[64];
    __shared__ float wsum[4];
    if (threadIdx.x < 64) sp[threadIdx.x] = prm[threadIdx.x];
    __syncthreads();

    int idx = blockIdx.x * 256 + threadIdx.x;   // < 2 * 2^22
    int b   = idx >> 22;
    int rem = idx & (NN - 1);
    int i   = rem >> 11;          // row  -> dy
    int j   = rem & (NSAMP - 1);  // col  -> dx

    float ni = fmaf((float)i, STEPf, -1024.0f) * DXf;
    float nj = fmaf((float)j, STEPf, -1024.0f) * DXf;

    float sh = 0.0f, ch = 0.0f;   // sum amp*sin, sum amp*cos (hat)
    float sg = 0.0f, cg = 0.0f;   // (gt)

    #pragma unroll
    for (int p = 0; p < 4; ++p) {
        const float* q = &sp[(b * 4 + p) * 8];
        float dx = nj - q[0] + EPSf;
        float dy = ni - q[1] + EPSf;
        float rho = sqrtf(dx * dx + dy * dy);
        float invrho = 1.0f / rho;
        float r2 = rho * rho;
        {   // predicted set
            float j1  = bessel_j1f(q[2] * rho);
            float amp = q[3] * invrho * j1;
            float s, c;
            sincosf(r2 * q[4], &s, &c);
            sh = fmaf(amp, s, sh);
            ch = fmaf(amp, c, ch);
        }
        {   // ground-truth set
            float j1  = bessel_j1f(q[5] * rho);
            float amp = q[6] * invrho * j1;
            float s, c;
            sincosf(r2 * q[7], &s, &c);
            sg = fmaf(amp, s, sg);
            cg = fmaf(amp, c, cg);
        }
    }
    // re = sum-1, im = -sum  (sign of im irrelevant after squaring)
    float reh = sh - 1.0f, reg = sg - 1.0f;
    float vh = reh * reh + ch * ch;
    float vg = reg * reg + cg * cg;
    float d  = vh - vg;
    float t  = d * d;

    // wave64 butterfly-free down-reduce, then cross-wave via LDS
    #pragma unroll
    for (int off = 32; off > 0; off >>= 1) t += __shfl_down(t, off, 64);
    if ((threadIdx.x & 63) == 0) wsum[threadIdx.x >> 6] = t;
    __syncthreads();
    if (threadIdx.x == 0) {
        float s = (wsum[0] + wsum[1]) + (wsum[2] + wsum[3]);
        atomicAdd(acc, (double)s);
    }
}

__global__ void finalize_kernel(const double* __restrict__ acc, float* __restrict__ out) {
    // mse * N^2 / 384^2 = sum / (B*N^2) * N^2/384^2 = sum / (2*384^2)
    out[0] = (float)(acc[0] / 294912.0);
}

extern "C" void kernel_launch(void* const* d_in, const int* in_sizes, int n_in,
                              void* d_out, int out_size, void* d_ws, size_t ws_size,
                              hipStream_t stream) {
    const float* yh  = (const float*)d_in[0];   // y_hat (2,3,512,512) f32
    const float* ygt = (const float*)d_in[1];   // y     (2,5,512,512) f32
    const int*   xs  = (const int*)d_in[2];     // (2,4) i32
    const int*   ys  = (const int*)d_in[3];     // (2,4) i32

    double* acc = (double*)d_ws;
    float*  prm = (float*)((char*)d_ws + 16);
    float*  out = (float*)d_out;

    gather_params_kernel<<<1, 64, 0, stream>>>(yh, ygt, xs, ys, prm, acc);
    holo_mse_kernel<<<(2 * NN) / 256, 256, 0, stream>>>(prm, acc);
    finalize_kernel<<<1, 1, 0, stream>>>(acc, out);
}

// Round 2
// 108.695 us; speedup vs baseline: 19.5660x; 19.5660x over previous
//
#include <hip/hip_runtime.h>
#include <math.h>

#ifndef M_PI
#define M_PI 3.14159265358979323846
#endif

// Problem constants (from the reference)
constexpr int    NSAMP  = 2048;
constexpr int    NN     = NSAMP * NSAMP;           // 2^22
constexpr float  STEPf  = 2048.0f / 2047.0f;       // linspace(-1024,1024,2048) step
constexpr float  DXf    = 6.0e-6f;                 // 3e-6 / 0.5
constexpr float  EPSf   = 2.2204e-16f;
constexpr double Kd     = 2.0 * M_PI / 3.55e-7;    // ~1.7698956e7
constexpr double INV2PI = 1.0 / (2.0 * M_PI);

// ---------------------------------------------------------------------------
// Gather per-(batch,particle) parameters; precompute revolution-domain consts.
// prm layout per (b,p), stride 16:
//  0:xm 1:ym
//  2:carg_h 3:cargrev_h 4:c8_h 5:c636_h 6:camp_h 7:cphrev_h   (predicted)
//  8:carg_g 9:cargrev_g 10:c8_g 11:c636_g 12:camp_g 13:cphrev_g (ground truth)
// ---------------------------------------------------------------------------
__global__ void gather_params_kernel(const float* __restrict__ yh,
                                     const float* __restrict__ ygt,
                                     const int*   __restrict__ xs,
                                     const int*   __restrict__ ys,
                                     float* __restrict__ prm,
                                     double* __restrict__ acc) {
    int t = threadIdx.x;
    if (t == 0) *acc = 0.0;   // zero accumulator every launch (graph replay safe)
    if (t < 8) {
        const int M = 512;
        int b = t >> 2, p = t & 3;
        int ix = xs[b * 4 + p];
        int iy = ys[b * 4 + p];
        float rs_h = 50.0f  * yh [((b * 3 + 2) * M + iy) * M + ix];
        float zs_h = 200.0f * yh [((b * 3 + 1) * M + iy) * M + ix];
        float rs_g =          ygt[((b * 5 + 2) * M + iy) * M + ix];
        float zs_g =          ygt[((b * 5 + 1) * M + iy) * M + ix];
        double rph = (double)rs_h * 1e-6, zph = (double)zs_h * 1e-3;
        double rpg = (double)rs_g * 1e-6, zpg = (double)zs_g * 1e-3;

        float* o = prm + t * 16;
        o[0] = ((float)(ix * 4) - 1024.0f) * DXf;   // xm
        o[1] = ((float)(iy * 4) - 1024.0f) * DXf;   // ym

        double carg_h = Kd * rph / zph;
        o[2] = (float)carg_h;
        o[3] = (float)(carg_h * INV2PI);
        o[4] = (float)(8.0 / carg_h);
        o[5] = (float)(0.636619772 / carg_h);
        o[6] = (float)(0.5 * rph);
        o[7] = (float)(Kd / (2.0 * zph) * INV2PI);

        double carg_g = Kd * rpg / zpg;
        o[8]  = (float)carg_g;
        o[9]  = (float)(carg_g * INV2PI);
        o[10] = (float)(8.0 / carg_g);
        o[11] = (float)(0.636619772 / carg_g);
        o[12] = (float)(0.5 * rpg);
        o[13] = (float)(Kd / (2.0 * zpg) * INV2PI);
        o[14] = 0.0f; o[15] = 0.0f;
    }
}

// One particle-set J1*trig contribution. All native-rate ops, branchless.
__device__ __forceinline__ void accum_set(float carg, float cargrev, float c8,
                                          float c636, float camp, float cphrev,
                                          float rho, float invr, float r2,
                                          float& S, float& C) {
    float x = carg * rho;
    // --- small branch (|x|<8), clamped like the reference's clip ---
    float xc  = fminf(x, 8.0f);
    float yy  = xc * xc;
    float num = xc * fmaf(yy, fmaf(yy, fmaf(yy, fmaf(yy, fmaf(yy,
                    -30.16036606f, 15704.48260f), -2972611.439f),
                    242396853.1f), -7895059235.0f), 72362614232.0f);
    float den = fmaf(yy, fmaf(yy, fmaf(yy, fmaf(yy, (yy + 376.9991397f),
                    99447.43394f), 18583304.74f), 2300535178.0f), 144725228442.0f);
    float j1s = num * __builtin_amdgcn_rcpf(den);
    // --- large branch (asymptotic), z = 8/x <= 1 when selected ---
    float z    = fminf(c8 * invr, 1.0f);     // clamp keeps unselected lanes finite
    float y2   = z * z;
    float rev1 = fmaf(cargrev, rho, -0.375f);    // (x - 3pi/4)/2pi
    float f1   = __builtin_amdgcn_fractf(rev1);
    float s1   = __builtin_amdgcn_sinf(f1);
    float c1   = __builtin_amdgcn_cosf(f1);
    float p1   = fmaf(y2, fmaf(y2, fmaf(y2, fmaf(y2, -0.240337019e-6f,
                     0.2457520174e-5f), -0.3516396496e-4f), 0.183105e-2f), 1.0f);
    float p2   = fmaf(y2, fmaf(y2, fmaf(y2, fmaf(y2, 0.105787412e-6f,
                     -0.88228987e-6f), 0.8449199096e-5f), -0.2002690873e-3f),
                     0.04687499995f);
    float sq   = __builtin_amdgcn_sqrtf(c636 * invr);
    float t2   = (z * s1) * p2;
    float j1l  = sq * fmaf(c1, p1, -t2);
    float j1v  = (x < 8.0f) ? j1s : j1l;
    // --- phase: rev = cphrev*r2, with FMA residual to recover low bits ---
    float hi  = cphrev * r2;
    float err = fmaf(cphrev, r2, -hi);
    float fr  = __builtin_amdgcn_fractf(hi) + err;
    float s2  = __builtin_amdgcn_sinf(fr);
    float c2  = __builtin_amdgcn_cosf(fr);
    float amp = camp * invr * j1v;
    S = fmaf(amp, s2, S);
    C = fmaf(amp, c2, C);
}

// 4096 blocks x 256 threads; each thread does 8 points (same j, rows i0+256k),
// block-uniform batch index.
__global__ __launch_bounds__(256, 4) void holo_mse_kernel(
        const float* __restrict__ prm, double* __restrict__ acc) {
    __shared__ float sp[128];
    __shared__ float wsum[4];
    if (threadIdx.x < 128) sp[threadIdx.x] = prm[threadIdx.x];
    __syncthreads();

    int blk = blockIdx.x;
    int b   = blk >> 11;                            // block-uniform batch
    int r   = ((blk & 2047) << 8) + threadIdx.x;    // [0, 524288)
    int i0  = r >> 11;                              // row base (0..255)
    int j   = r & (NSAMP - 1);

    float nj = fmaf((float)j, STEPf, -1024.0f) * DXf;
    float ni[8];
    #pragma unroll
    for (int k = 0; k < 8; ++k)
        ni[k] = fmaf((float)(i0 + 256 * k), STEPf, -1024.0f) * DXf;

    float Sh[8], Ch[8], Sg[8], Cg[8];
    #pragma unroll
    for (int k = 0; k < 8; ++k) { Sh[k] = Ch[k] = Sg[k] = Cg[k] = 0.0f; }

    const float* P = &sp[b * 64];
    #pragma unroll
    for (int p = 0; p < 4; ++p) {
        const float* q = &P[p * 16];
        float xm = q[0], ym = q[1];
        float carg_h = q[2], cargrev_h = q[3], c8_h = q[4],
              c636_h = q[5], camp_h = q[6], cphrev_h = q[7];
        float carg_g = q[8], cargrev_g = q[9], c8_g = q[10],
              c636_g = q[11], camp_g = q[12], cphrev_g = q[13];
        float dx  = nj - xm + EPSf;
        float dx2 = dx * dx;
        #pragma unroll
        for (int k = 0; k < 8; ++k) {
            float dy   = ni[k] - ym + EPSf;
            float r2   = fmaf(dy, dy, dx2);
            float invr = __builtin_amdgcn_rsqf(r2);
            float rho  = r2 * invr;
            accum_set(carg_h, cargrev_h, c8_h, c636_h, camp_h, cphrev_h,
                      rho, invr, r2, Sh[k], Ch[k]);
            accum_set(carg_g, cargrev_g, c8_g, c636_g, camp_g, cphrev_g,
                      rho, invr, r2, Sg[k], Cg[k]);
        }
    }

    float accd = 0.0f;
    #pragma unroll
    for (int k = 0; k < 8; ++k) {
        float reh = Sh[k] - 1.0f, reg = Sg[k] - 1.0f;
        float vh  = fmaf(reh, reh, Ch[k] * Ch[k]);
        float vg  = fmaf(reg, reg, Cg[k] * Cg[k]);
        float d   = vh - vg;
        accd = fmaf(d, d, accd);
    }

    #pragma unroll
    for (int off = 32; off > 0; off >>= 1) accd += __shfl_down(accd, off, 64);
    if ((threadIdx.x & 63) == 0) wsum[threadIdx.x >> 6] = accd;
    __syncthreads();
    if (threadIdx.x == 0) {
        float s = (wsum[0] + wsum[1]) + (wsum[2] + wsum[3]);
        atomicAdd(acc, (double)s);
    }
}

__global__ void finalize_kernel(const double* __restrict__ acc, float* __restrict__ out) {
    // mse * N^2 / 384^2 = sum / (B*N^2) * N^2/384^2 = sum / (2*384^2)
    out[0] = (float)(acc[0] / 294912.0);
}

extern "C" void kernel_launch(void* const* d_in, const int* in_sizes, int n_in,
                              void* d_out, int out_size, void* d_ws, size_t ws_size,
                              hipStream_t stream) {
    const float* yh  = (const float*)d_in[0];   // y_hat (2,3,512,512) f32
    const float* ygt = (const float*)d_in[1];   // y     (2,5,512,512) f32
    const int*   xs  = (const int*)d_in[2];     // (2,4) i32
    const int*   ys  = (const int*)d_in[3];     // (2,4) i32

    double* acc = (double*)d_ws;
    float*  prm = (float*)((char*)d_ws + 16);
    float*  out = (float*)d_out;

    gather_params_kernel<<<1, 128, 0, stream>>>(yh, ygt, xs, ys, prm, acc);
    holo_mse_kernel<<<4096, 256, 0, stream>>>(prm, acc);
    finalize_kernel<<<1, 1, 0, stream>>>(acc, out);
}